// Round 3
// 868.725 us; speedup vs baseline: 1.0379x; 1.0379x over previous
//
#include <hip/hip_runtime.h>
#include <hip/hip_fp16.h>

// NGP fwd: per-hashed-level encode (L2-resident fp16 table) + fp16-MFMA MLP.
// N = 4,194,304 points. Table: [16, 2^19, 2] fp32. Levels 0-5 dense, 6-15 hashed.
// fp16 activations carry a global scale S=4096 (bias-free MLP + ReLU => scale
// transparent; removed at final store).
// LDS transpose: ALL accesses volatile + __syncthreads barriers. The buffer is
// type-punned (u32 writes / f16x8 reads); without volatile, TBAA lets the
// compiler hoist or CSE a slice of ds_reads across ds_writes (R5/R6:
// one-of-64-features stale => 2-4e-5 structural error).
// R7/R8 (FAILED, reverted): replacing __syncthreads with wave-local
// "s_waitcnt lgkmcnt(0)"+sched_barrier(0) produced 7.4e-6 structural error
// despite the buffer being wave-private — rule-#18-class scheduler/asm
// interaction not fully understood. K2 stays on proven __syncthreads.
// R9: K1 is the majority cost (~578us of 901) and sits at the L2
// line-request throughput ceiling (16.8M random 4B gathers/level). tcnn 2D
// hash uses PRIME1=1, so for even x0: (x0+1)^hy == (x0^hy)^1 -> both
// x-corners live in one aligned 8B pair of the fp16 table. Even-x0 lanes
// (50%) load 2x8B instead of 4x4B => expected L2 requests x0.75.
// R9: nt hints kept on K0/K1 streaming traffic (pos reads, feat/table
// writes) to protect the 2MB table's L2 residency. nt is an eviction
// priority hint on CDNA (coherent through L2) — value-neutral.

constexpr unsigned TSIZE  = 1u << 19;
constexpr unsigned PRIME2 = 2654435761u;
constexpr int N_HASHED    = 10;      // levels 6..15
constexpr int LVL0_HASH   = 6;
#define FEAT_SCALE   4096.0f
#define INV_SCALE    (1.0f / 4096.0f)

typedef _Float16 f16x8 __attribute__((ext_vector_type(8)));
typedef float    f32x4 __attribute__((ext_vector_type(4)));
typedef unsigned u32x2 __attribute__((ext_vector_type(2)));
typedef unsigned u32x4 __attribute__((ext_vector_type(4)));

__device__ __forceinline__ unsigned pkh2(float a, float b) {
    __half2 h = __floats2half2_rn(a, b);
    unsigned u; __builtin_memcpy(&u, &h, 4); return u;
}

__device__ __forceinline__ float2 h2f(unsigned u) {
    __half2 h; __builtin_memcpy(&h, &u, 4);
    return __half22float2(h);
}

// ---------- K0: hashed-level tables fp32 -> fp16*S (into ws) ----------
__global__ __launch_bounds__(256)
void cvt_table(const float* __restrict__ src, unsigned* __restrict__ dst, int n2)
{
    int t = blockIdx.x * blockDim.x + threadIdx.x;
    if (t >= n2) return;
    f32x4 v = __builtin_nontemporal_load((const f32x4*)src + t);
    u32x2 pk;
    pk.x = pkh2(v.x * FEAT_SCALE, v.y * FEAT_SCALE);
    pk.y = pkh2(v.z * FEAT_SCALE, v.w * FEAT_SCALE);
    __builtin_nontemporal_store(pk, (u32x2*)dst + t);
}

// ---------- K1: one hashed level -> fp16 feats (level-major, scaled) ----------
// Table viewed as u32 entries (packed half2). Even-x0 pair trick: for x0
// even, i10 = i00^1, so one aligned 8B load covers both x-corners.
__device__ __forceinline__ unsigned hash_feat(float px, float py, float scale,
                                              const unsigned* __restrict__ tblu)
{
    float pxs = fmaf(px, scale, 0.5f);
    float pys = fmaf(py, scale, 0.5f);
    float fx = floorf(pxs), fy = floorf(pys);
    float wx = pxs - fx,   wy = pys - fy;
    unsigned x0 = (unsigned)fx, y0 = (unsigned)fy;

    unsigned hy0 = y0 * PRIME2;
    unsigned hy1 = hy0 + PRIME2;
    unsigned i00 = (x0 ^ hy0) & (TSIZE - 1u);
    unsigned i01 = (x0 ^ hy1) & (TSIZE - 1u);

    unsigned u00, u10, u01, u11;
    if ((x0 & 1u) == 0u) {
        // x0 even: {i00, i00^1} = {t00, t10} in one aligned 8B pair.
        u32x2 pa = *(const u32x2*)(tblu + (i00 & ~1u));
        u32x2 pb = *(const u32x2*)(tblu + (i01 & ~1u));
        u00 = (i00 & 1u) ? pa.y : pa.x;
        u10 = (i00 & 1u) ? pa.x : pa.y;
        u01 = (i01 & 1u) ? pb.y : pb.x;
        u11 = (i01 & 1u) ? pb.x : pb.y;
    } else {
        unsigned i10 = ((x0 + 1u) ^ hy0) & (TSIZE - 1u);
        unsigned i11 = ((x0 + 1u) ^ hy1) & (TSIZE - 1u);
        u00 = tblu[i00];
        u10 = tblu[i10];
        u01 = tblu[i01];
        u11 = tblu[i11];
    }

    float2 c00 = h2f(u00), c10 = h2f(u10), c01 = h2f(u01), c11 = h2f(u11);

    float w00 = (1.0f - wx) * (1.0f - wy);
    float w10 = wx * (1.0f - wy);
    float w01 = (1.0f - wx) * wy;
    float w11 = wx * wy;

    float f0 = w00 * c00.x + w10 * c10.x + w01 * c01.x + w11 * c11.x;
    float f1 = w00 * c00.y + w10 * c10.y + w01 * c01.y + w11 * c11.y;

    return pkh2(f0, f1);   // table already scaled by S
}

__global__ __launch_bounds__(256)
void encode_level(const float* __restrict__ pos,
                  const unsigned* __restrict__ tblu,
                  u32x2* __restrict__ feat,
                  int nhalf, unsigned res)
{
    int t = blockIdx.x * blockDim.x + threadIdx.x;
    if (t >= nhalf) return;
    f32x4 p = __builtin_nontemporal_load((const f32x4*)pos + t);
    float scale = (float)res - 1.0f;
    unsigned a = hash_feat(p.x, p.y, scale, tblu);
    unsigned b = hash_feat(p.z, p.w, scale, tblu);
    u32x2 pk = {a, b};
    __builtin_nontemporal_store(pk, feat + t);
}

// ---------- K2: coarse levels + fp16 MFMA MLP (transposed layers) ----------
// Per wave: 64 points. All layers as D^T = W^T * act^T:
//   A-frag = weight tile (once per wave), A[m=lane&15][k=q*8+j].
//   B-frag lane&15 = point, k = q*8+j.
//   C/D: col(lane&15)=point, row=(lane>>4)*4+reg = feature.
// One 9216 B wave-private buffer reused feats->h1->h2; volatile + barriers.
// PROVEN R0 structure: lockstep uniform trip count + __syncthreads.
#define S0B 80    // act0 row stride bytes  (40 halfs)
#define S1B 144   // act1/2 row stride bytes (72 halfs)

__global__ __launch_bounds__(256)
void mlp_mfma(const float* __restrict__ pos,
              const float* __restrict__ table,
              const unsigned* __restrict__ feats,  // [10][N] half2 as uint, scaled
              const float* __restrict__ W1,        // [32,64]
              const float* __restrict__ W2,        // [64,64]
              const float* __restrict__ W3,        // [64,3]
              float* __restrict__ out, int n)
{
    __shared__ uint4 lds[4 * 9216 / 16];
    const int lane = threadIdx.x & 63;
    const int wid  = threadIdx.x >> 6;
    const int m    = lane & 15;      // point-within-tile (B/N index)
    const int q    = lane >> 4;      // quad
    char* buf = (char*)lds + wid * 9216;

    // ---- weight A-frags (once per wave) ----
    f16x8 A1[4];
#pragma unroll
    for (int ft = 0; ft < 4; ft++)
#pragma unroll
        for (int j = 0; j < 8; j++)
            A1[ft][j] = (_Float16)W1[(q * 8 + j) * 64 + ft * 16 + m];

    f16x8 A2[4][2];
#pragma unroll
    for (int ft = 0; ft < 4; ft++)
#pragma unroll
        for (int kb = 0; kb < 2; kb++)
#pragma unroll
            for (int j = 0; j < 8; j++)
                A2[ft][kb][j] = (_Float16)W2[(kb * 32 + q * 8 + j) * 64 + ft * 16 + m];

    f16x8 A3[2];
#pragma unroll
    for (int kb = 0; kb < 2; kb++)
#pragma unroll
        for (int j = 0; j < 8; j++)
            A3[kb][j] = (m < 3) ? (_Float16)W3[(kb * 32 + q * 8 + j) * 3 + m]
                                : (_Float16)0.f;

    const int ntiles  = n >> 6;
    const int wstride = gridDim.x * 4;
    const int niter   = (ntiles + wstride - 1) / wstride;   // uniform trip count

    for (int it = 0; it < niter; it++) {
        const int t = blockIdx.x * 4 + wid + it * wstride;
        const bool active = (t < ntiles);
        const int p0 = t << 6;
        const int p  = p0 + lane;

        // ---- P0: this lane's 32 features (fp16-packed, scaled) -> LDS ----
        if (active) {
            unsigned fl[16];
            float px = pos[2 * p], py = pos[2 * p + 1];
#pragma unroll
            for (int lvl = 0; lvl < 6; lvl++) {
                const unsigned res = 16u << lvl;
                const float scale = (float)res - 1.0f;
                float pxs = fmaf(px, scale, 0.5f);
                float pys = fmaf(py, scale, 0.5f);
                float fx = floorf(pxs), fy = floorf(pys);
                float wx = pxs - fx,   wy = pys - fy;
                unsigned x0 = (unsigned)fx, y0 = (unsigned)fy;
                unsigned i00 = x0 + y0 * res;
                const float* tl = table + (size_t)lvl * (size_t)TSIZE * 2u;
                float2 t00 = *(const float2*)(tl + 2u * i00);
                float2 t10 = *(const float2*)(tl + 2u * (i00 + 1u));
                float2 t01 = *(const float2*)(tl + 2u * (i00 + res));
                float2 t11 = *(const float2*)(tl + 2u * (i00 + res + 1u));
                float w00 = (1.0f - wx) * (1.0f - wy);
                float w10 = wx * (1.0f - wy);
                float w01 = (1.0f - wx) * wy;
                float w11 = wx * wy;
                float f0 = fmaf(w00, t00.x, fmaf(w10, t10.x, fmaf(w01, t01.x, w11 * t11.x)));
                float f1 = fmaf(w00, t00.y, fmaf(w10, t10.y, fmaf(w01, t01.y, w11 * t11.y)));
                fl[lvl] = pkh2(f0 * FEAT_SCALE, f1 * FEAT_SCALE);
            }
#pragma unroll
            for (int l = 0; l < N_HASHED; l++)
                fl[6 + l] = feats[(size_t)l * (size_t)n + p];

            volatile u32x4* w = (volatile u32x4*)(buf + lane * S0B);
            u32x4 w0 = {fl[0],  fl[1],  fl[2],  fl[3]};
            u32x4 w1 = {fl[4],  fl[5],  fl[6],  fl[7]};
            u32x4 w2 = {fl[8],  fl[9],  fl[10], fl[11]};
            u32x4 w3 = {fl[12], fl[13], fl[14], fl[15]};
            w[0] = w0; w[1] = w1; w[2] = w2; w[3] = w3;
        }
        __syncthreads();   // feats visible before B1 reads

        f16x8 B1[4];
        if (active) {
#pragma unroll
            for (int pt = 0; pt < 4; pt++)
                B1[pt] = *(volatile const f16x8*)(buf + (pt * 16 + m) * S0B + q * 16);
        }
        __syncthreads();   // all B1 reads done before h1 overwrites buffer

        if (active) {
#pragma unroll
            for (int ft = 0; ft < 4; ft++) {
#pragma unroll
                for (int pt = 0; pt < 4; pt++) {
                    f32x4 acc = {0.f, 0.f, 0.f, 0.f};
                    acc = __builtin_amdgcn_mfma_f32_16x16x32_f16(A1[ft], B1[pt], acc, 0, 0, 0);
                    u32x2 pk = {pkh2(fmaxf(acc[0], 0.f), fmaxf(acc[1], 0.f)),
                                pkh2(fmaxf(acc[2], 0.f), fmaxf(acc[3], 0.f))};
                    *(volatile u32x2*)(buf + (pt * 16 + m) * S1B + (ft * 16 + q * 4) * 2) = pk;
                }
            }
        }
        __syncthreads();   // h1 visible before B2 reads

        f16x8 B2[4][2];
        if (active) {
#pragma unroll
            for (int pt = 0; pt < 4; pt++)
#pragma unroll
                for (int kb = 0; kb < 2; kb++)
                    B2[pt][kb] = *(volatile const f16x8*)(buf + (pt * 16 + m) * S1B + kb * 64 + q * 16);
        }
        __syncthreads();   // all B2 reads done before h2 overwrites buffer

        if (active) {
#pragma unroll
            for (int ft = 0; ft < 4; ft++) {
#pragma unroll
                for (int pt = 0; pt < 4; pt++) {
                    f32x4 acc = {0.f, 0.f, 0.f, 0.f};
                    acc = __builtin_amdgcn_mfma_f32_16x16x32_f16(A2[ft][0], B2[pt][0], acc, 0, 0, 0);
                    acc = __builtin_amdgcn_mfma_f32_16x16x32_f16(A2[ft][1], B2[pt][1], acc, 0, 0, 0);
                    u32x2 pk = {pkh2(fmaxf(acc[0], 0.f), fmaxf(acc[1], 0.f)),
                                pkh2(fmaxf(acc[2], 0.f), fmaxf(acc[3], 0.f))};
                    *(volatile u32x2*)(buf + (pt * 16 + m) * S1B + (ft * 16 + q * 4) * 2) = pk;
                }
            }
        }
        __syncthreads();   // h2 visible before B3 reads

        if (active) {
            f16x8 B3[4][2];
#pragma unroll
            for (int pt = 0; pt < 4; pt++)
#pragma unroll
                for (int kb = 0; kb < 2; kb++)
                    B3[pt][kb] = *(volatile const f16x8*)(buf + (pt * 16 + m) * S1B + kb * 64 + q * 16);

#pragma unroll
            for (int pt = 0; pt < 4; pt++) {
                f32x4 acc = {0.f, 0.f, 0.f, 0.f};
                acc = __builtin_amdgcn_mfma_f32_16x16x32_f16(A3[0], B3[pt][0], acc, 0, 0, 0);
                acc = __builtin_amdgcn_mfma_f32_16x16x32_f16(A3[1], B3[pt][1], acc, 0, 0, 0);
                if (q == 0) {
                    int po = p0 + pt * 16 + m;
                    out[3 * po + 0] = acc[0] * INV_SCALE;
                    out[3 * po + 1] = acc[1] * INV_SCALE;
                    out[3 * po + 2] = acc[2] * INV_SCALE;
                }
            }
        }
        __syncthreads();   // B3 reads done before next tile's feat writes
    }
}

// ---------- Fallback: monolithic fp32 (used if ws too small / odd n) ----------
__global__ __launch_bounds__(256, 2)
void ngp_mono(const float* __restrict__ pos, const float* __restrict__ table,
              const float* __restrict__ W1, const float* __restrict__ W2,
              const float* __restrict__ W3, float* __restrict__ out, int n)
{
    int i = blockIdx.x * blockDim.x + threadIdx.x;
    if (i >= n) return;
    float px = pos[2 * i], py = pos[2 * i + 1];
    float h1[64];
#pragma unroll
    for (int j = 0; j < 64; j++) h1[j] = 0.0f;
#pragma unroll
    for (int lvl = 0; lvl < 16; lvl++) {
        const unsigned res = 16u << lvl;
        const float scale = (float)res - 1.0f;
        float pxs = fmaf(px, scale, 0.5f);
        float pys = fmaf(py, scale, 0.5f);
        float fx = floorf(pxs), fy = floorf(pys);
        float wx = pxs - fx, wy = pys - fy;
        unsigned x0 = (unsigned)fx, y0 = (unsigned)fy;
        unsigned i00, i10, i01, i11;
        if ((unsigned long long)res * (unsigned long long)res <= (unsigned long long)TSIZE) {
            i00 = x0 + y0 * res; i10 = i00 + 1u; i01 = i00 + res; i11 = i01 + 1u;
        } else {
            unsigned hy0 = y0 * PRIME2, hy1 = (y0 + 1u) * PRIME2;
            i00 = (x0 ^ hy0) & (TSIZE - 1u);
            i10 = ((x0 + 1u) ^ hy0) & (TSIZE - 1u);
            i01 = (x0 ^ hy1) & (TSIZE - 1u);
            i11 = ((x0 + 1u) ^ hy1) & (TSIZE - 1u);
        }
        const float* tl = table + (size_t)lvl * (size_t)TSIZE * 2u;
        float2 t00 = *(const float2*)(tl + 2u * i00);
        float2 t10 = *(const float2*)(tl + 2u * i10);
        float2 t01 = *(const float2*)(tl + 2u * i01);
        float2 t11 = *(const float2*)(tl + 2u * i11);
        float w00 = (1.0f - wx) * (1.0f - wy);
        float w10 = wx * (1.0f - wy);
        float w01 = (1.0f - wx) * wy;
        float w11 = wx * wy;
        float f0 = fmaf(w00, t00.x, fmaf(w10, t10.x, fmaf(w01, t01.x, w11 * t11.x)));
        float f1 = fmaf(w00, t00.y, fmaf(w10, t10.y, fmaf(w01, t01.y, w11 * t11.y)));
        const float* w1r0 = W1 + (2 * lvl) * 64;
        const float* w1r1 = W1 + (2 * lvl + 1) * 64;
#pragma unroll
        for (int j = 0; j < 64; j++)
            h1[j] = fmaf(f0, w1r0[j], fmaf(f1, w1r1[j], h1[j]));
    }
#pragma unroll
    for (int j = 0; j < 64; j++) h1[j] = fmaxf(h1[j], 0.0f);
    float h2[64];
#pragma unroll
    for (int j = 0; j < 64; j++) h2[j] = 0.0f;
#pragma unroll
    for (int k = 0; k < 64; k++) {
        float a = h1[k];
        const float* wr = W2 + k * 64;
#pragma unroll
        for (int j = 0; j < 64; j++) h2[j] = fmaf(a, wr[j], h2[j]);
    }
#pragma unroll
    for (int j = 0; j < 64; j++) h2[j] = fmaxf(h2[j], 0.0f);
    float o0 = 0.0f, o1 = 0.0f, o2 = 0.0f;
#pragma unroll
    for (int k = 0; k < 64; k++) {
        float a = h2[k];
        o0 = fmaf(a, W3[k * 3 + 0], o0);
        o1 = fmaf(a, W3[k * 3 + 1], o1);
        o2 = fmaf(a, W3[k * 3 + 2], o2);
    }
    out[3 * i + 0] = o0; out[3 * i + 1] = o1; out[3 * i + 2] = o2;
}

extern "C" void kernel_launch(void* const* d_in, const int* in_sizes, int n_in,
                              void* d_out, int out_size, void* d_ws, size_t ws_size,
                              hipStream_t stream) {
    const float* pos   = (const float*)d_in[0];
    const float* table = (const float*)d_in[1];
    const float* W1    = (const float*)d_in[2];
    const float* W2    = (const float*)d_in[3];
    const float* W3    = (const float*)d_in[4];
    float* out = (float*)d_out;

    int n = in_sizes[0] / 2;

    size_t tbl16_bytes = (size_t)N_HASHED * TSIZE * 4u;            // 20 MB
    size_t feats_bytes = (size_t)N_HASHED * (size_t)n * 4u;        // 168 MB
    size_t need = tbl16_bytes + feats_bytes;

    if (ws_size < need || (n & 511)) {
        int blocks = (n + 255) / 256;
        hipLaunchKernelGGL(ngp_mono, dim3(blocks), dim3(256), 0, stream,
                           pos, table, W1, W2, W3, out, n);
        return;
    }

    unsigned* tbl16 = (unsigned*)d_ws;
    __half2* feats  = (__half2*)((char*)d_ws + tbl16_bytes);

    // K0: fp32 -> fp16*S table conversion for hashed levels
    {
        int n2 = (N_HASHED * TSIZE) / 2;
        int blocks = (n2 + 255) / 256;
        hipLaunchKernelGGL(cvt_table, dim3(blocks), dim3(256), 0, stream,
                           table + (size_t)LVL0_HASH * TSIZE * 2u, tbl16, n2);
    }

    // K1 x10: one hashed level at a time (keeps 2 MB table L2-resident)
    {
        int nhalf = n / 2;
        int blocks = (nhalf + 255) / 256;
        for (int l = 0; l < N_HASHED; l++) {
            const unsigned* tbl_l = tbl16 + (size_t)l * TSIZE;
            u32x2* feat_l = (u32x2*)(feats + (size_t)l * (size_t)n);
            unsigned res = 16u << (l + LVL0_HASH);
            hipLaunchKernelGGL(encode_level, dim3(blocks), dim3(256), 0, stream,
                               pos, tbl_l, feat_l, nhalf, res);
        }
    }

    // K2: coarse levels + fp16 MFMA MLP
    {
        hipLaunchKernelGGL(mlp_mfma, dim3(1024), dim3(256), 0, stream,
                           pos, table, (const unsigned*)feats, W1, W2, W3, out, n);
    }
}